// Round 9
// baseline (263.067 us; speedup 1.0000x reference)
//
#include <hip/hip_runtime.h>
#include <stdint.h>

#define M_DIM 8192
#define N_DIM 4096
#define K_DIM 4096
#define QMAXF 127.0f
#define QDIVF 127.5f

typedef int v4i __attribute__((ext_vector_type(4)));

// ---------------- address-space helpers for global_load_lds ----------------
typedef __attribute__((address_space(3))) void lds_void_t;
typedef __attribute__((address_space(1))) const void glb_void_t;

static __device__ __forceinline__ void load_lds16(const void* g, void* l) {
    __builtin_amdgcn_global_load_lds((glb_void_t*)g, (lds_void_t*)l, 16, 0, 0);
}

// ---- kernel 1: fused prep pass 1: [row absmax+quant lhs] ∥ [col absmax rhs] ----
__global__ __launch_bounds__(256) void prep1_kernel(
        const float* __restrict__ lhs, const float* __restrict__ rhs,
        float* __restrict__ sL, unsigned* __restrict__ bits,
        int8_t* __restrict__ ql) {
    const int t = threadIdx.x;
    if (blockIdx.x < M_DIM) {
        const int row = blockIdx.x;
        const float4* rp = (const float4*)(lhs + (size_t)row * K_DIM);
        float4 v[4];
        float m = 0.0f;
#pragma unroll
        for (int i = 0; i < 4; ++i) {
            v[i] = rp[t + i * 256];
            m = fmaxf(m, fmaxf(fmaxf(fabsf(v[i].x), fabsf(v[i].y)),
                               fmaxf(fabsf(v[i].z), fabsf(v[i].w))));
        }
#pragma unroll
        for (int off = 32; off; off >>= 1) m = fmaxf(m, __shfl_down(m, off, 64));
        __shared__ float wmax[4];
        if ((t & 63) == 0) wmax[t >> 6] = m;
        __syncthreads();
        const float mm = fmaxf(fmaxf(wmax[0], wmax[1]), fmaxf(wmax[2], wmax[3]));
        float s = mm / QDIVF;
        s = (s == 0.0f) ? 1.0f : s;
        if (t == 0) sL[row] = s;
        unsigned* qo = (unsigned*)ql + (size_t)row * 1024;
#pragma unroll
        for (int i = 0; i < 4; ++i) {
            int q0 = (int)fminf(fmaxf(rintf(v[i].x / s), -QMAXF), QMAXF);
            int q1 = (int)fminf(fmaxf(rintf(v[i].y / s), -QMAXF), QMAXF);
            int q2 = (int)fminf(fmaxf(rintf(v[i].z / s), -QMAXF), QMAXF);
            int q3 = (int)fminf(fmaxf(rintf(v[i].w / s), -QMAXF), QMAXF);
            qo[t + i * 256] = (q0 & 255) | ((q1 & 255) << 8) | ((q2 & 255) << 16)
                            | ((unsigned)(q3 & 255) << 24);
        }
    } else {
        const int cb = blockIdx.x - M_DIM;     // 0..1023
        const int col = (cb & 15) * 256 + t;
        const int r0 = (cb >> 4) * 64;
        float m = 0.0f;
#pragma unroll 4
        for (int r = 0; r < 64; ++r)
            m = fmaxf(m, fabsf(rhs[(size_t)(r0 + r) * N_DIM + col]));
        atomicMax(&bits[col], __float_as_uint(m));   // abs >= 0: bit order == float order
    }
}

// -- kernel 2: quantize + transpose rhs -> q_rT [N][K]; also materialize sR --
__global__ __launch_bounds__(256) void quant_rhs_t_kernel(
        const float* __restrict__ rhs, const unsigned* __restrict__ bits,
        float* __restrict__ sR, int8_t* __restrict__ qbT) {
    __shared__ __align__(16) int8_t lt[64][80];
    const int n0 = blockIdx.x * 64;
    const int k0 = blockIdx.y * 64;
    const int t = threadIdx.x;
    const int nloc = t & 63;
    const int kq = (t >> 6) * 16;
    float s = __uint_as_float(bits[n0 + nloc]) / QDIVF;
    s = (s == 0.0f) ? 1.0f : s;
    if (blockIdx.y == 0 && t < 64) {
        float ss = __uint_as_float(bits[n0 + t]) / QDIVF;
        sR[n0 + t] = (ss == 0.0f) ? 1.0f : ss;
    }
#pragma unroll
    for (int i = 0; i < 4; ++i) {
        unsigned pack = 0;
#pragma unroll
        for (int j = 0; j < 4; ++j) {
            int kk = kq + i * 4 + j;
            float x = rhs[(size_t)(k0 + kk) * N_DIM + n0 + nloc];
            int q = (int)fminf(fmaxf(rintf(x / s), -QMAXF), QMAXF);
            pack |= (unsigned)(q & 255) << (8 * j);
        }
        *(unsigned*)&lt[nloc][kq + i * 4] = pack;
    }
    __syncthreads();
    const int nn = t >> 2, ch = t & 3;
    v4i val = *(const v4i*)&lt[nn][ch * 16];
    *(v4i*)&qbT[(size_t)(n0 + nn) * K_DIM + k0 + ch * 16] = val;
}

// ===== kernel 3: int8 GEMM, 256x256, BK=64, A-in-registers / B-in-LDS =====
// R8 falsified the schedule hypothesis: MFMA and LDS pipe cycles sum to the
// wall across 6 structures (HW serialization). Fix: remove A from LDS.
// A-frags load straight global->VGPR (same 64B/row pattern staging used;
// L2-resident panel). LDS holds only B: ring-4 x 16KB. Per tile: issue
// A(kt+1)->regs + stage B(kt+2)->LDS; ds_read B(kt) frags (staged 2 tiles
// ago, published by barrier); 32 MFMA; VMCNT(6); barrier. vmcnt queue at the
// wait: [A(kt)x4 (auto-waited pre-MFMA), B(kt+1)x2, A(kt+1)x4, B(kt+2)x2]
// -> <=6 drains B(kt+1) for next tile's post-barrier reads.
// 8 waves (4M x 2N), per-wave 64x128 = 4mf x 8nf of mfma_i32_16x16x64_i8.
// B swizzle (validated, conflict-free): phys_chunk = c ^ ((row>>1)&3) on
// BOTH stage-source and ds_read.

#define BAR() do { asm volatile("" ::: "memory");          \
                   __builtin_amdgcn_s_barrier();           \
                   asm volatile("" ::: "memory"); } while (0)

#define VMCNT(N) asm volatile("s_waitcnt vmcnt(%0)" :: "n"(N) : "memory")

// TILE: BUF = KT & 3, PAR = KT & 1 (compile-time). SA: load A(KT+1).
// SB: stage B(KT+2). VM: counted wait before barrier.
#define TILE(KT, BUF, PAR, SA, SB, VM) do {                                     \
    if (SA) {                                                                   \
        _Pragma("unroll") for (int mm = 0; mm < 4; ++mm)                        \
            an[(PAR) ^ 1][mm] = *(const v4i*)(pa[mm] + ((KT) + 1) * 64);        \
    }                                                                           \
    if (SB) {                                                                   \
        load_lds16(gB0 + (size_t)((KT) + 2) * 64,                               \
                   lds + (((KT) + 2) & 3) * 16384 + sdst);                      \
        load_lds16(gB0 + (size_t)128 * K_DIM + (size_t)((KT) + 2) * 64,         \
                   lds + (((KT) + 2) & 3) * 16384 + 8192 + sdst);               \
    }                                                                           \
    _Pragma("unroll") for (int nn = 0; nn < 8; ++nn)                            \
        bf[nn] = *(const v4i*)(lds + (BUF) * 16384 + boff[nn]);                 \
    __builtin_amdgcn_s_setprio(1);                                              \
    _Pragma("unroll") for (int mm = 0; mm < 4; ++mm)                            \
    _Pragma("unroll") for (int nn = 0; nn < 8; ++nn)                            \
        acc[mm][nn] = __builtin_amdgcn_mfma_i32_16x16x64_i8(                    \
            an[PAR][mm], bf[nn], acc[mm][nn], 0, 0, 0);                         \
    __builtin_amdgcn_s_setprio(0);                                              \
    VMCNT(VM);                                                                  \
    BAR();                                                                      \
} while (0)

__global__ __launch_bounds__(512, 2) void gemm_i8_kernel(
        const int8_t* __restrict__ qa, const int8_t* __restrict__ qbT,
        const float* __restrict__ sL, const float* __restrict__ sR,
        float* __restrict__ out) {
    __shared__ __align__(16) int8_t lds[65536];   // B only: 4 bufs x 16KB

    const int t = threadIdx.x;
    const int wave = t >> 6;
    const int lane = t & 63;

    // XCD partition: xcd owns 8mt x 8nt; consecutive idx share mt (A-panel
    // 1MB stays L2-resident while its 8 nt-blocks run). Bijective, 512 blocks.
    const int bid = blockIdx.x;
    const int xcd = bid & 7;
    const int idx = bid >> 3;                     // 0..63
    const int mt = (xcd >> 1) * 8 + (idx >> 3);   // 0..31
    const int nt = (xcd & 1) * 8 + (idx & 7);     // 0..15
    const int brow = mt * 256;
    const int bcol = nt * 256;

    const int wm = (wave >> 1) * 64;     // 4 M-groups of 64 rows
    const int wn = (wave & 1) * 128;     // 2 N-groups of 128 cols

    // A-frag global base pointers (per mf): row = brow+wm+mf*16+(lane&15),
    // 16B at k-offset (lane>>4)*16; tile KT adds KT*64.
    const int8_t* pa[4];
#pragma unroll
    for (int m = 0; m < 4; ++m)
        pa[m] = qa + (size_t)(brow + wm + m * 16 + (lane & 15)) * K_DIM
                   + (lane >> 4) * 16;

    // B fragment read byte-offsets (within a 16KB buf; swizzled; 64B rows)
    int boff[8];
#pragma unroll
    for (int n = 0; n < 8; ++n) {
        int row = wn + n * 16 + (lane & 15);
        boff[n] = row * 64 + (((lane >> 4) ^ ((row >> 1) & 3)) * 16);
    }

    v4i acc[4][8];
#pragma unroll
    for (int m = 0; m < 4; ++m)
#pragma unroll
        for (int n = 0; n < 8; ++n) acc[m][n] = (v4i){0, 0, 0, 0};

    // B staging: thread t covers bytes [t*16, t*16+16) of an 8KB half
    // (128 rows x 64B); source chunk pre-swizzled so linear LDS holds the
    // swizzled layout.
    const int srow = t >> 2;                                  // 0..127
    const int lcA = (t & 3) ^ ((srow >> 1) & 3);
    const int8_t* gB0 = qbT + (size_t)(bcol + srow) * K_DIM + lcA * 16;
    const int sdst = t * 16;

    v4i an[2][4], bf[8];

    // prologue: stage B0->buf0, B1->buf1; load A0 frags; drain B0; publish.
    load_lds16(gB0,                             lds + sdst);
    load_lds16(gB0 + (size_t)128 * K_DIM,       lds + 8192 + sdst);
    load_lds16(gB0 + 64,                        lds + 16384 + sdst);
    load_lds16(gB0 + (size_t)128 * K_DIM + 64,  lds + 16384 + 8192 + sdst);
#pragma unroll
    for (int mm = 0; mm < 4; ++mm) an[0][mm] = *(const v4i*)(pa[mm]);
    VMCNT(6);   // drain B0 LDS writes; A0 is auto-waited before first MFMA
    BAR();

    for (int kt = 0; kt < 60; kt += 4) {
        TILE(kt + 0, 0, 0, 1, 1, 6);
        TILE(kt + 1, 1, 1, 1, 1, 6);
        TILE(kt + 2, 2, 0, 1, 1, 6);
        TILE(kt + 3, 3, 1, 1, 1, 6);
    }
    TILE(60, 0, 0, 1, 1, 6);   // loads A61, stages B62
    TILE(61, 1, 1, 1, 1, 6);   // loads A62, stages B63
    TILE(62, 2, 0, 1, 0, 4);   // loads A63; drains B63 (A63 may stay in flight)
    TILE(63, 3, 1, 0, 0, 0);

    // Epilogue (validated): 16x16 C/D: col = lane&15, row = (lane>>4)*4 + reg
    const int r4 = (lane >> 4) * 4;
    const int cc = lane & 15;
#pragma unroll
    for (int m = 0; m < 4; ++m) {
        const int grow0 = brow + wm + m * 16 + r4;
        const float s0 = sL[grow0 + 0];
        const float s1 = sL[grow0 + 1];
        const float s2 = sL[grow0 + 2];
        const float s3 = sL[grow0 + 3];
#pragma unroll
        for (int n = 0; n < 8; ++n) {
            const int gcol = bcol + wn + n * 16 + cc;
            const float sc = sR[gcol];
            float* o = out + (size_t)grow0 * N_DIM + gcol;
            o[0 * N_DIM] = (float)acc[m][n][0] * s0 * sc;
            o[1 * N_DIM] = (float)acc[m][n][1] * s1 * sc;
            o[2 * N_DIM] = (float)acc[m][n][2] * s2 * sc;
            o[3 * N_DIM] = (float)acc[m][n][3] * s3 * sc;
        }
    }
}

// ---------------- launch ----------------
extern "C" void kernel_launch(void* const* d_in, const int* in_sizes, int n_in,
                              void* d_out, int out_size, void* d_ws, size_t ws_size,
                              hipStream_t stream) {
    const float* lhs = (const float*)d_in[0];
    const float* rhs = (const float*)d_in[1];
    float* out = (float*)d_out;

    uint8_t* ws = (uint8_t*)d_ws;
    int8_t* ql    = (int8_t*)ws;                               // 33,554,432 B
    int8_t* qbT   = (int8_t*)(ws + 33554432);                  // 16,777,216 B
    float* sL     = (float*)(ws + 50331648);                   // 32,768 B
    float* sR     = (float*)(ws + 50331648 + 32768);           // 16,384 B
    unsigned* bits = (unsigned*)(ws + 50331648 + 32768 + 16384); // 16,384 B

    hipMemsetAsync(bits, 0, N_DIM * sizeof(unsigned), stream);

    prep1_kernel<<<M_DIM + 1024, 256, 0, stream>>>(lhs, rhs, sL, bits, ql);
    quant_rhs_t_kernel<<<dim3(N_DIM / 64, K_DIM / 64), 256, 0, stream>>>(
        rhs, bits, sR, qbT);
    gemm_i8_kernel<<<dim3((M_DIM / 256) * (N_DIM / 256)), 512, 0, stream>>>(
        ql, qbT, sL, sR, out);
}

// Round 10
// 210.914 us; speedup vs baseline: 1.2473x; 1.2473x over previous
//
#include <hip/hip_runtime.h>
#include <stdint.h>

#define M_DIM 8192
#define N_DIM 4096
#define K_DIM 4096
#define QMAXF 127.0f
#define QDIVF 127.5f

typedef int v4i __attribute__((ext_vector_type(4)));

// ---------------- address-space helpers for global_load_lds ----------------
typedef __attribute__((address_space(3))) void lds_void_t;
typedef __attribute__((address_space(1))) const void glb_void_t;

static __device__ __forceinline__ void load_lds16(const void* g, void* l) {
    __builtin_amdgcn_global_load_lds((glb_void_t*)g, (lds_void_t*)l, 16, 0, 0);
}

// ---- kernel 1: fused prep pass 1: [row absmax+quant lhs] ∥ [col absmax rhs] ----
__global__ __launch_bounds__(256) void prep1_kernel(
        const float* __restrict__ lhs, const float* __restrict__ rhs,
        float* __restrict__ sL, unsigned* __restrict__ bits,
        int8_t* __restrict__ ql) {
    const int t = threadIdx.x;
    if (blockIdx.x < M_DIM) {
        const int row = blockIdx.x;
        const float4* rp = (const float4*)(lhs + (size_t)row * K_DIM);
        float4 v[4];
        float m = 0.0f;
#pragma unroll
        for (int i = 0; i < 4; ++i) {
            v[i] = rp[t + i * 256];
            m = fmaxf(m, fmaxf(fmaxf(fabsf(v[i].x), fabsf(v[i].y)),
                               fmaxf(fabsf(v[i].z), fabsf(v[i].w))));
        }
#pragma unroll
        for (int off = 32; off; off >>= 1) m = fmaxf(m, __shfl_down(m, off, 64));
        __shared__ float wmax[4];
        if ((t & 63) == 0) wmax[t >> 6] = m;
        __syncthreads();
        const float mm = fmaxf(fmaxf(wmax[0], wmax[1]), fmaxf(wmax[2], wmax[3]));
        float s = mm / QDIVF;
        s = (s == 0.0f) ? 1.0f : s;
        if (t == 0) sL[row] = s;
        unsigned* qo = (unsigned*)ql + (size_t)row * 1024;
#pragma unroll
        for (int i = 0; i < 4; ++i) {
            int q0 = (int)fminf(fmaxf(rintf(v[i].x / s), -QMAXF), QMAXF);
            int q1 = (int)fminf(fmaxf(rintf(v[i].y / s), -QMAXF), QMAXF);
            int q2 = (int)fminf(fmaxf(rintf(v[i].z / s), -QMAXF), QMAXF);
            int q3 = (int)fminf(fmaxf(rintf(v[i].w / s), -QMAXF), QMAXF);
            qo[t + i * 256] = (q0 & 255) | ((q1 & 255) << 8) | ((q2 & 255) << 16)
                            | ((unsigned)(q3 & 255) << 24);
        }
    } else {
        const int cb = blockIdx.x - M_DIM;     // 0..1023
        const int col = (cb & 15) * 256 + t;
        const int r0 = (cb >> 4) * 64;
        float m = 0.0f;
#pragma unroll 4
        for (int r = 0; r < 64; ++r)
            m = fmaxf(m, fabsf(rhs[(size_t)(r0 + r) * N_DIM + col]));
        atomicMax(&bits[col], __float_as_uint(m));   // abs >= 0: bit order == float order
    }
}

// -- kernel 2: quantize + transpose rhs -> q_rT [N][K]; also materialize sR --
__global__ __launch_bounds__(256) void quant_rhs_t_kernel(
        const float* __restrict__ rhs, const unsigned* __restrict__ bits,
        float* __restrict__ sR, int8_t* __restrict__ qbT) {
    __shared__ __align__(16) int8_t lt[64][80];
    const int n0 = blockIdx.x * 64;
    const int k0 = blockIdx.y * 64;
    const int t = threadIdx.x;
    const int nloc = t & 63;
    const int kq = (t >> 6) * 16;
    float s = __uint_as_float(bits[n0 + nloc]) / QDIVF;
    s = (s == 0.0f) ? 1.0f : s;
    if (blockIdx.y == 0 && t < 64) {
        float ss = __uint_as_float(bits[n0 + t]) / QDIVF;
        sR[n0 + t] = (ss == 0.0f) ? 1.0f : ss;
    }
#pragma unroll
    for (int i = 0; i < 4; ++i) {
        unsigned pack = 0;
#pragma unroll
        for (int j = 0; j < 4; ++j) {
            int kk = kq + i * 4 + j;
            float x = rhs[(size_t)(k0 + kk) * N_DIM + n0 + nloc];
            int q = (int)fminf(fmaxf(rintf(x / s), -QMAXF), QMAXF);
            pack |= (unsigned)(q & 255) << (8 * j);
        }
        *(unsigned*)&lt[nloc][kq + i * 4] = pack;
    }
    __syncthreads();
    const int nn = t >> 2, ch = t & 3;
    v4i val = *(const v4i*)&lt[nn][ch * 16];
    *(v4i*)&qbT[(size_t)(n0 + nn) * K_DIM + k0 + ch * 16] = val;
}

// == kernel 3: int8 GEMM, 256x256, BK=64, m201-faithful 4-phase/tile, ring-3 ==
// Per tile kt (buf = kt%3), phases with SMALL clumps (the m201 lever):
//  p0: read A[0-3](mh0) + B[0-1]; stage A0(kt+2); BAR; 8 MFMA (mh0 x nh0); BAR
//  p1: read B[2-3];               stage A1(kt+2); BAR; 8 MFMA (mh0 x nh1); BAR
//  p2: read A[0-3]<-mh1;          stage B0(kt+2); BAR; 8 MFMA (mh1 x nh0); BAR
//  p3:                            stage B1(kt+2); VMCNT(4); BAR; 8 MFMA; BAR
// vmcnt(4) at p3 leaves tile kt+2's 4 halves in flight (~1 tile of slack);
// drains tile kt+1 so its post-barrier reads are race-free for ALL waves.
// WAR: buf (kt+2)%3 == buf (kt-1)%3; its last reads lgkm-completed >=2
// barriers before the overwriting stage. 8 waves (2M x 4N), per-wave 128x64
// = 8mf x 4nf of mfma_i32_16x16x64_i8. Swizzle/staging/epilogue: validated.

#define BAR() do { asm volatile("" ::: "memory");          \
                   __builtin_amdgcn_s_barrier();           \
                   asm volatile("" ::: "memory"); } while (0)

#define VMCNT(N) asm volatile("s_waitcnt vmcnt(%0)" :: "n"(N) : "memory")

#define RD_A(BUF, MF) (*(const v4i*)(lds + (BUF) * 32768 + aoff[MF]))
#define RD_B(BUF, NF) (*(const v4i*)(lds + (BUF) * 32768 + boff[NF]))

// stage one 8KB half of tile KT into buf (KT)%3 region OFF (A0=0, A1=8192,
// B0=16384, B1=24576); PTR in {gA0, gA1, gB0, gB1}
#define STAGE_H(PTR, KT, OFF) \
    load_lds16((PTR) + (size_t)(KT) * 64, lds + ((KT) % 3) * 32768 + (OFF) + sdst8)

#define MFMA8(MB, NB)                                                           \
    _Pragma("unroll") for (int mm = 0; mm < 4; ++mm)                            \
    _Pragma("unroll") for (int nn = 0; nn < 2; ++nn)                            \
        acc[(MB) + mm][(NB) + nn] = __builtin_amdgcn_mfma_i32_16x16x64_i8(      \
            af[mm], bf[(NB) + nn], acc[(MB) + mm][(NB) + nn], 0, 0, 0);

#define TILE8(KT, BUF, S, VMLAST) do {                                          \
    /* ---- p0 ---- */                                                          \
    _Pragma("unroll") for (int mm = 0; mm < 4; ++mm) af[mm] = RD_A(BUF, mm);    \
    bf[0] = RD_B(BUF, 0); bf[1] = RD_B(BUF, 1);                                 \
    if (S) STAGE_H(gA0, (KT) + 2, 0);                                           \
    BAR();                                                                      \
    __builtin_amdgcn_s_setprio(1); MFMA8(0, 0); __builtin_amdgcn_s_setprio(0);  \
    BAR();                                                                      \
    /* ---- p1 ---- */                                                          \
    bf[2] = RD_B(BUF, 2); bf[3] = RD_B(BUF, 3);                                 \
    if (S) STAGE_H(gA1, (KT) + 2, 8192);                                        \
    BAR();                                                                      \
    __builtin_amdgcn_s_setprio(1); MFMA8(0, 2); __builtin_amdgcn_s_setprio(0);  \
    BAR();                                                                      \
    /* ---- p2 ---- */                                                          \
    _Pragma("unroll") for (int mm = 0; mm < 4; ++mm) af[mm] = RD_A(BUF, 4 + mm);\
    if (S) STAGE_H(gB0, (KT) + 2, 16384);                                       \
    BAR();                                                                      \
    __builtin_amdgcn_s_setprio(1); MFMA8(4, 0); __builtin_amdgcn_s_setprio(0);  \
    BAR();                                                                      \
    /* ---- p3 ---- */                                                          \
    if (S) STAGE_H(gB1, (KT) + 2, 24576);                                       \
    VMCNT(VMLAST);                                                              \
    BAR();                                                                      \
    __builtin_amdgcn_s_setprio(1); MFMA8(4, 2); __builtin_amdgcn_s_setprio(0);  \
    BAR();                                                                      \
} while (0)

__global__ __launch_bounds__(512, 2) void gemm_i8_kernel(
        const int8_t* __restrict__ qa, const int8_t* __restrict__ qbT,
        const float* __restrict__ sL, const float* __restrict__ sR,
        float* __restrict__ out) {
    __shared__ __align__(16) int8_t lds[98304];   // 3 bufs x (A 16KB + B 16KB)

    const int t = threadIdx.x;
    const int wave = t >> 6;
    const int lane = t & 63;

    // 2D XCD partition (R7-validated): each XCD owns 8mt x 8nt. Bijective.
    const int bid = blockIdx.x;
    const int xcd = bid & 7;
    const int idx = bid >> 3;                    // 0..63
    const int mt = (xcd >> 1) * 8 + (idx & 7);   // 0..31
    const int nt = (xcd & 1) * 8 + (idx >> 3);   // 0..15
    const int brow = mt * 256;
    const int bcol = nt * 256;

    const int wm = (wave >> 2) * 128;    // 2 M-groups of 128 rows
    const int wn = (wave & 3) * 64;      // 4 N-groups of 64 cols

    // fragment read byte-offsets (within buf; swizzled; 64B rows)
    // A region [0,16KB): rows 0-255; B region [16KB,32KB): rows 0-255.
    int aoff[8], boff[4];
#pragma unroll
    for (int m = 0; m < 8; ++m) {
        int row = wm + m * 16 + (lane & 15);
        aoff[m] = row * 64 + (((lane >> 4) ^ ((row >> 1) & 3)) * 16);
    }
#pragma unroll
    for (int n = 0; n < 4; ++n) {
        int row = wn + n * 16 + (lane & 15);
        boff[n] = 16384 + row * 64 + (((lane >> 4) ^ ((row >> 1) & 3)) * 16);
    }

    v4i acc[8][4];
#pragma unroll
    for (int m = 0; m < 8; ++m)
#pragma unroll
        for (int n = 0; n < 4; ++n) acc[m][n] = (v4i){0, 0, 0, 0};

    // staging: 512 threads x 16B = one 8KB half (128 rows x 64B) per stage.
    // source chunk pre-swizzled so linear LDS holds the swizzled layout.
    const int srow = t >> 2;                                  // 0..127
    const int lcA = (t & 3) ^ ((srow >> 1) & 3);
    const int8_t* gA0 = qa  + (size_t)(brow + srow) * K_DIM + lcA * 16;
    const int8_t* gA1 = gA0 + (size_t)128 * K_DIM;
    const int8_t* gB0 = qbT + (size_t)(bcol + srow) * K_DIM + lcA * 16;
    const int8_t* gB1 = gB0 + (size_t)128 * K_DIM;
    const int sdst8 = t * 16;

    v4i af[4], bf[4];

    // prologue: stage tiles 0 (buf0) and 1 (buf1); drain tile 0; publish.
    STAGE_H(gA0, 0, 0); STAGE_H(gA1, 0, 8192);
    STAGE_H(gB0, 0, 16384); STAGE_H(gB1, 0, 24576);
    STAGE_H(gA0, 1, 0); STAGE_H(gA1, 1, 8192);
    STAGE_H(gB0, 1, 16384); STAGE_H(gB1, 1, 24576);
    VMCNT(4);
    BAR();

    for (int kt = 0; kt < 60; kt += 3) {
        TILE8(kt + 0, 0, 1, 4);
        TILE8(kt + 1, 1, 1, 4);
        TILE8(kt + 2, 2, 1, 4);
    }
    TILE8(60, 0, 1, 4);   // stages T62
    TILE8(61, 1, 1, 4);   // stages T63
    TILE8(62, 2, 0, 0);   // drain: T63 resident
    TILE8(63, 0, 0, 0);

    // Epilogue (validated): 16x16 C/D: col = lane&15, row = (lane>>4)*4 + reg
    const int r4 = (lane >> 4) * 4;
    const int cc = lane & 15;
#pragma unroll
    for (int m = 0; m < 8; ++m) {
        const int grow0 = brow + wm + m * 16 + r4;
        const float s0 = sL[grow0 + 0];
        const float s1 = sL[grow0 + 1];
        const float s2 = sL[grow0 + 2];
        const float s3 = sL[grow0 + 3];
#pragma unroll
        for (int n = 0; n < 4; ++n) {
            const int gcol = bcol + wn + n * 16 + cc;
            const float sc = sR[gcol];
            float* o = out + (size_t)grow0 * N_DIM + gcol;
            o[0 * N_DIM] = (float)acc[m][n][0] * s0 * sc;
            o[1 * N_DIM] = (float)acc[m][n][1] * s1 * sc;
            o[2 * N_DIM] = (float)acc[m][n][2] * s2 * sc;
            o[3 * N_DIM] = (float)acc[m][n][3] * s3 * sc;
        }
    }
}

// ---------------- launch ----------------
extern "C" void kernel_launch(void* const* d_in, const int* in_sizes, int n_in,
                              void* d_out, int out_size, void* d_ws, size_t ws_size,
                              hipStream_t stream) {
    const float* lhs = (const float*)d_in[0];
    const float* rhs = (const float*)d_in[1];
    float* out = (float*)d_out;

    uint8_t* ws = (uint8_t*)d_ws;
    int8_t* ql    = (int8_t*)ws;                               // 33,554,432 B
    int8_t* qbT   = (int8_t*)(ws + 33554432);                  // 16,777,216 B
    float* sL     = (float*)(ws + 50331648);                   // 32,768 B
    float* sR     = (float*)(ws + 50331648 + 32768);           // 16,384 B
    unsigned* bits = (unsigned*)(ws + 50331648 + 32768 + 16384); // 16,384 B

    hipMemsetAsync(bits, 0, N_DIM * sizeof(unsigned), stream);

    prep1_kernel<<<M_DIM + 1024, 256, 0, stream>>>(lhs, rhs, sL, bits, ql);
    quant_rhs_t_kernel<<<dim3(N_DIM / 64, K_DIM / 64), 256, 0, stream>>>(
        rhs, bits, sR, qbT);
    gemm_i8_kernel<<<dim3((M_DIM / 256) * (N_DIM / 256)), 512, 0, stream>>>(
        ql, qbT, sL, sR, out);
}